// Round 4
// baseline (326.974 us; speedup 1.0000x reference)
//
#include <hip/hip_runtime.h>
#include <hip/hip_fp16.h>

typedef _Float16 half_t;
typedef _Float16 half8 __attribute__((ext_vector_type(8)));
typedef float floatx4 __attribute__((ext_vector_type(4)));

static constexpr int BATCH = 2;
static constexpr int NSP = 4096;   // H*W
static constexpr int CH = 512;
static constexpr int NQKV = 3 * CH;  // 1536
static constexpr int KSPLIT = 4;

// ---- ws layout (bytes) ----
static constexpr size_t OFF_STATS = 0;                              // 128 floats
static constexpr size_t OFF_ROWSUM = 512;                           // B*NSP floats (32 KB)
static constexpr size_t OFF_PST = 33280;                            // GN partials
static constexpr size_t OFF_WQKV = 196608;
static constexpr size_t WQKV_BYTES = (size_t)NQKV * CH * 2;         // 1.5 MB
static constexpr size_t OFF_WP = OFF_WQKV + WQKV_BYTES;
static constexpr size_t WP_BYTES = (size_t)CH * CH * 2;             // 0.5 MB
static constexpr size_t OFF_XN = OFF_WP + WP_BYTES;
static constexpr size_t XN_BYTES = (size_t)BATCH * NSP * CH * 2;    // 8 MB
static constexpr size_t OFF_QKV = OFF_XN + XN_BYTES;
static constexpr size_t QKV_BYTES = (size_t)BATCH * NSP * NQKV * 2; // 24 MB
static constexpr size_t OFF_VT = OFF_QKV + QKV_BYTES;
static constexpr size_t OFF_AO = OFF_VT + XN_BYTES;
static constexpr size_t OFF_S = OFF_AO + XN_BYTES;
// fused attention PV partials: 8 slabs x 4 MB = 32 MB in the (now unused)
// S region -- MUST NOT overlay qkv/vt (live during fattn).
static constexpr size_t OFF_PART = OFF_S;

__device__ __forceinline__ void gld16(void* lds, const void* g) {
  __builtin_amdgcn_global_load_lds(
      (__attribute__((address_space(1))) void*)(g),
      (__attribute__((address_space(3))) void*)(lds),
      16, 0, 0);
}

#define VMCNT(n) asm volatile("s_waitcnt vmcnt(" #n ")" ::: "memory")
#define LGKM0()                                         \
  do {                                                  \
    asm volatile("s_waitcnt lgkmcnt(0)" ::: "memory");  \
    __builtin_amdgcn_sched_barrier(0);                  \
  } while (0)

// ---------------- GroupNorm ----------------
__global__ __launch_bounds__(256) void gn_stats(const float* __restrict__ x,
                                                float* __restrict__ pst) {
  int b = blockIdx.y;
  int tid = (int)threadIdx.x;
  int g = ((tid * 4) & (CH - 1)) >> 4;
  const float* base = x + (long)b * NSP * CH + (long)blockIdx.x * 16 * CH + tid * 4;
  float s = 0.f, s2 = 0.f;
#pragma unroll
  for (int it = 0; it < 8; ++it) {
    floatx4 v = *(const floatx4*)(base + (long)it * 1024);
#pragma unroll
    for (int r = 0; r < 4; ++r) { s += v[r]; s2 += v[r] * v[r]; }
  }
  __shared__ float gs[32], gs2[32];
  if (tid < 32) { gs[tid] = 0.f; gs2[tid] = 0.f; }
  __syncthreads();
  atomicAdd(&gs[g], s);
  atomicAdd(&gs2[g], s2);
  __syncthreads();
  if (tid < 32) {
    long idx = ((long)(b * 256 + blockIdx.x) * 32 + tid) * 2;
    pst[idx] = gs[tid];
    pst[idx + 1] = gs2[tid];
  }
}

__global__ __launch_bounds__(256) void gn_finalize(const float* __restrict__ pst,
                                                   float* __restrict__ st,
                                                   float* __restrict__ rowsum) {
  int tid = (int)threadIdx.x;
  int bg = tid & 63;
  int p = tid >> 6;
  int b = bg >> 5, g = bg & 31;
  float s = 0.f, s2 = 0.f;
  for (int j = 0; j < 64; ++j) {
    int chunk = p * 64 + j;
    long idx = ((long)(b * 256 + chunk) * 32 + g) * 2;
    s += pst[idx];
    s2 += pst[idx + 1];
  }
  __shared__ float rs[64][4], rs2[64][4];
  rs[bg][p] = s;
  rs2[bg][p] = s2;
  __syncthreads();
  if (tid < 64) {
    float ts = rs[tid][0] + rs[tid][1] + rs[tid][2] + rs[tid][3];
    float ts2 = rs2[tid][0] + rs2[tid][1] + rs2[tid][2] + rs2[tid][3];
    const float inv = 1.f / 65536.f;
    float mean = ts * inv;
    float var = ts2 * inv - mean * mean;
    st[tid * 2] = mean;
    st[tid * 2 + 1] = rsqrtf(var + 1e-5f);
  }
  floatx4* rz = (floatx4*)rowsum;
#pragma unroll
  for (int j = 0; j < 8; ++j)
    rz[tid + j * 256] = floatx4{0.f, 0.f, 0.f, 0.f};
}

__global__ __launch_bounds__(256) void gn_apply(const float* __restrict__ x,
                                                const float* __restrict__ st,
                                                const float* __restrict__ gamma,
                                                const float* __restrict__ beta,
                                                half_t* __restrict__ xn) {
  long i = ((long)blockIdx.x * 256 + threadIdx.x) * 8;
  int c = (int)(i & (CH - 1));
  int b = (int)(i >> 21);
  int g = c >> 4;
  float mean = st[((b << 5) + g) * 2];
  float rstd = st[((b << 5) + g) * 2 + 1];
  floatx4 a = *(const floatx4*)(x + i);
  floatx4 d = *(const floatx4*)(x + i + 4);
  half8 o;
#pragma unroll
  for (int r = 0; r < 4; ++r) {
    o[r]     = (half_t)((a[r] - mean) * rstd * gamma[c + r] + beta[c + r]);
    o[r + 4] = (half_t)((d[r] - mean) * rstd * gamma[c + r + 4] + beta[c + r + 4]);
  }
  *(half8*)(xn + i) = o;
}

// ---------------- transposes ----------------
__global__ __launch_bounds__(256) void transpose_w(
    const float* __restrict__ w0, const float* __restrict__ w1,
    const float* __restrict__ w2, const float* __restrict__ w3,
    half_t* __restrict__ o0, half_t* __restrict__ o1,
    half_t* __restrict__ o2, half_t* __restrict__ o3) {
  const float* w; half_t* o;
  switch (blockIdx.z) {
    case 0: w = w0; o = o0; break;
    case 1: w = w1; o = o1; break;
    case 2: w = w2; o = o2; break;
    default: w = w3; o = o3; break;
  }
  __shared__ float t[32][33];
  int d0 = blockIdx.x * 32, c0 = blockIdx.y * 32;
  int tx = threadIdx.x & 31, ty = threadIdx.x >> 5;
#pragma unroll
  for (int i = 0; i < 4; ++i)
    t[ty + i * 8][tx] = w[(long)(c0 + ty + i * 8) * CH + d0 + tx];
  __syncthreads();
#pragma unroll
  for (int i = 0; i < 4; ++i) {
    int d = ty + i * 8;
    o[(long)(d0 + d) * CH + c0 + tx] = (half_t)t[tx][d];
  }
}

__global__ __launch_bounds__(256) void transpose_v(const half_t* __restrict__ v,
                                                   half_t* __restrict__ vt) {
  __shared__ half_t t[32][33];
  int b = blockIdx.z;
  int d0 = blockIdx.x * 32, n0 = blockIdx.y * 32;
  int tx = threadIdx.x & 31, ty = threadIdx.x >> 5;
  const half_t* vb = v + (long)b * NSP * NQKV;
  half_t* ob = vt + (long)b * NSP * CH;
#pragma unroll
  for (int i = 0; i < 4; ++i)
    t[ty + i * 8][tx] = vb[(long)(n0 + ty + i * 8) * NQKV + d0 + tx];
  __syncthreads();
#pragma unroll
  for (int i = 0; i < 4; ++i) {
    int d = ty + i * 8;
    ob[(long)(d0 + d) * NSP + n0 + tx] = t[tx][d];
  }
}

// ---------------- NT GEMM (QKV + proj) ----------------
template <int BM, int BN, int BK, int EPI, int SWZ, int KSP, typename OutT>
__global__ __launch_bounds__(256) void gemm_nt(
    const half_t* __restrict__ X, const half_t* __restrict__ Y,
    OutT* __restrict__ Co, const float* __restrict__ b0,
    const float* __restrict__ b1, const float* __restrict__ b2,
    const float* __restrict__ resid, float* __restrict__ rowsum,
    int M, int N, int K, int ldx, int ldy, int ldc,
    long xbs, long ybs, long cbs, float scale) {
  constexpr int SM = BM / 32;
  constexpr int SN = BN / 32;
  constexpr int ROWS = BM + BN;
  constexpr int CPR = BK / 8;
  constexpr int RPW = 64 / CPR;
  constexpr int ROUNDS = (ROWS * BK * 2) / 4096;
  constexpr int KSTEPS = BK / 32;
  static_assert(BM % (4 * RPW) == 0, "no As/Bs straddle within a round");
  __shared__ __align__(16) half_t Sh[ROWS * BK];

  const int zb = blockIdx.z / KSP;
  const int ks = blockIdx.z % KSP;
  int bx, by;
  if (SWZ == 1) {
    int lin = (int)(blockIdx.x + gridDim.x * blockIdx.y);
    int wmt = 256 / (int)gridDim.x;
    by = wmt * (lin >> 8) + ((lin & 255) % wmt);
    bx = (lin & 255) / wmt;
  } else if (SWZ == 2) {
    by = blockIdx.x;
    bx = blockIdx.y;
  } else {
    bx = blockIdx.x;
    by = blockIdx.y;
  }

  const half_t* Xb = X + (long)zb * xbs + (long)ks * K;
  const half_t* Yb = Y + (long)zb * ybs + (long)ks * K;
  OutT* Cb = Co + (long)blockIdx.z * cbs;

  const int m0 = by * BM;
  const int n0 = bx * BN;
  const int tid = (int)threadIdx.x;
  const int wave = tid >> 6;
  const int lane = tid & 63;
  const int quad = lane >> 4;
  const int l16 = lane & 15;
  const int wm = wave >> 1;
  const int wn = wave & 1;

  floatx4 acc[SM][SN] = {};

  const int srow = lane / CPR;
  const int schunk = lane % CPR;
  const char* Xc = (const char*)Xb;

  int soff[ROUNDS];
#pragma unroll
  for (int r = 0; r < ROUNDS; ++r) {
    int row = r * (4 * RPW) + wave * RPW + srow;
    int gchunk = schunk ^ (row & (CPR - 1));
    const char* p = (row < BM)
        ? (const char*)(Xb + (long)(m0 + row) * ldx)
        : (const char*)(Yb + (long)(n0 + row - BM) * ldy);
    soff[r] = (int)(p + gchunk * 16 - Xc);
  }

  int offA[SM], offB[SN];
#pragma unroll
  for (int i = 0; i < SM; ++i) {
    int m = wm * (BM / 2) + i * 16 + l16;
    int cc = quad ^ (m & (CPR - 1));
    offA[i] = (m * BK + cc * 8) * 2;
  }
#pragma unroll
  for (int j = 0; j < SN; ++j) {
    int n = wn * (BN / 2) + j * 16 + l16;
    int cc = quad ^ (n & (CPR - 1));
    offB[j] = (BM * BK + n * BK + cc * 8) * 2;
  }

  for (int k0 = 0; k0 < K; k0 += BK) {
#pragma unroll
    for (int r = 0; r < ROUNDS; ++r) {
      gld16((char*)Sh + (r * 4 + wave) * 1024, Xc + (long)soff[r]);
      soff[r] += BK * 2;
    }
    __syncthreads();

#pragma unroll
    for (int kk = 0; kk < KSTEPS; ++kk) {
      const int kx = kk << 6;
      half8 af[SM], bf[SN];
#pragma unroll
      for (int i = 0; i < SM; ++i)
        af[i] = *(const half8*)((const char*)Sh + (offA[i] ^ kx));
#pragma unroll
      for (int j = 0; j < SN; ++j)
        bf[j] = *(const half8*)((const char*)Sh + (offB[j] ^ kx));
#pragma unroll
      for (int i = 0; i < SM; ++i)
#pragma unroll
        for (int j = 0; j < SN; ++j)
          acc[i][j] = __builtin_amdgcn_mfma_f32_16x16x32_f16(af[i], bf[j], acc[i][j], 0, 0, 0);
    }
    __syncthreads();
  }

#pragma unroll
  for (int i = 0; i < SM; ++i) {
    int gmb = m0 + wm * (BM / 2) + i * 16 + quad * 4;
#pragma unroll
    for (int j = 0; j < SN; ++j) {
      int gn = n0 + wn * (BN / 2) + j * 16 + l16;
      float bias = 0.f, sc = 1.f;
      if (EPI == 1) {
        if (gn < CH) { bias = b0[gn]; sc = scale; }
        else if (gn < 2 * CH) { bias = b1[gn - CH]; }
        else { bias = b2[gn - 2 * CH]; }
      } else if (EPI == 2) {
        bias = b0[gn];
      }
#pragma unroll
      for (int r = 0; r < 4; ++r) {
        long idx = (long)(gmb + r) * ldc + gn;
        float v = acc[i][j][r];
        if (EPI == 1) v = (v + bias) * sc;
        if (EPI == 2) v = v + bias + resid[idx];
        Cb[idx] = (OutT)v;
      }
    }
  }
}

// ---------------- fused flash attention ----------------
// Per block: 128 Q rows (one batch), KV range ksp*1024..+1023, 8 kv-iters of
// KVBLK=128. Per iter: QK^T (16 ksteps BK=32) -> exp -> P in LDS -> PV
// (4 psteps BK=32) accumulating O[128x512] in regs. Unnormalized partials +
// rowsum atomics; pv_combine divides.
// LDS (128KB, regions fully disjoint):
//   sbuf dbuf 2x16KB @0/@16384   (Q 128 rows + K 128 rows, 64B/row, paired
//                                 into 128B units, slot = e ^ (unit&7))
//   vbuf dbuf 2x32KB @32768/@65536 (VT 512 d-rows x 32 kv)
//   P 32KB @98304 ([128][128] half, 16B-chunk swizzle ^ (m&15))
// Staging hazards: dbuf parity + vmcnt(0)/barrier per kstep; cross-phase
// prefetch: VT pk0 staged at QK ks15; next-iter QK ks0 staged at PV pk3.
// NOTE r3 bugfix: offV is RELATIVE to vcur (was absolute +32768 -> odd
// psteps read the P region, even psteps the wrong vbuf).
__global__ __launch_bounds__(512, 2) void fattn(
    const half_t* __restrict__ Q, const half_t* __restrict__ Kp,
    const half_t* __restrict__ VT, half_t* __restrict__ part,
    float* __restrict__ rowsum) {
  __shared__ __align__(16) char smem[131072];
  const int zb = (int)blockIdx.x >> 5;
  const int mt = (int)blockIdx.x & 31;
  const int ksp = (int)blockIdx.y;
  const int m0 = mt * 128;
  const int kv0 = ksp * (NSP / KSPLIT);
  const int tid = (int)threadIdx.x;
  const int w = tid >> 6;
  const int l = tid & 63;
  const int quad = l >> 4;
  const int l16 = l & 15;
  const int wm = w >> 2;   // 0..1: Q-row half
  const int wn = w & 3;    // QK^T col quarter (32 wide)
  const int wd = w & 3;    // PV d quarter (128 wide)

  const char* Qc = (const char*)(Q + (long)zb * NSP * NQKV);
  const char* Kc = (const char*)(Kp + (long)zb * NSP * NQKV);
  const char* Vc = (const char*)(VT + (long)zb * NSP * CH);

  // per-lane staging source byte offsets
  int soffQ, soffK, soffV[4];
  {
    const int lu = l >> 3, le = l & 7;
    int u = w * 8 + lu;                  // 0..63
    int e = le ^ (u & 7);
    int R = (u << 1) | (e >> 2);         // Q row 0..127
    soffQ = ((m0 + R) * NQKV + (e & 3) * 8) * 2;
    u = 64 + w * 8 + lu;                 // 64..127
    e = le ^ (u & 7);
    R = ((u << 1) | (e >> 2)) - 128;     // K row 0..127 within tile
    soffK = ((kv0 + R) * NQKV + (e & 3) * 8) * 2;
#pragma unroll
    for (int r = 0; r < 4; ++r) {
      u = r * 64 + w * 8 + lu;           // 0..255
      e = le ^ (u & 7);
      R = (u << 1) | (e >> 2);           // d row 0..511
      soffV[r] = (R * NSP + kv0 + (e & 3) * 8) * 2;
    }
  }

  // LDS fragment read offsets
  int offA[4], offB[2], offV[8], offP0[4];
#pragma unroll
  for (int i = 0; i < 4; ++i) {
    const int R = wm * 64 + i * 16 + l16;
    offA[i] = (R >> 1) * 128 + (((((R & 1) << 2) | quad) ^ ((R >> 1) & 7)) << 4);
    offP0[i] = 98304 + R * 256 + ((quad ^ (R & 15)) << 4);
  }
#pragma unroll
  for (int j = 0; j < 2; ++j) {
    const int R = 128 + wn * 32 + j * 16 + l16;
    offB[j] = (R >> 1) * 128 + (((((R & 1) << 2) | quad) ^ ((R >> 1) & 7)) << 4);
  }
#pragma unroll
  for (int jj = 0; jj < 8; ++jj) {
    const int R = wd * 128 + jj * 16 + l16;
    // RELATIVE to vcur (r3 bugfix)
    offV[jj] = (R >> 1) * 128 + (((((R & 1) << 2) | quad) ^ ((R >> 1) & 7)) << 4);
  }

  floatx4 acc_o[4][8] = {};
  float rs[4][4] = {};

  // prologue: stage iter0 ks0 -> sbuf0
  gld16(smem + w * 1024, Qc + (long)soffQ);
  gld16(smem + (8 + w) * 1024, Kc + (long)soffK);
  soffQ += 64; soffK += 64;
  VMCNT(0);
  __builtin_amdgcn_s_barrier();

  for (int it = 0; it < 8; ++it) {
    floatx4 acc_s[4][2] = {};
    // ---- QK^T ----
#pragma unroll
    for (int ks = 0; ks < 16; ++ks) {
      const char* scur = smem + (ks & 1) * 16384;
      if (ks < 15) {
        char* sn = smem + ((ks + 1) & 1) * 16384;
        gld16(sn + w * 1024, Qc + (long)soffQ);
        gld16(sn + (8 + w) * 1024, Kc + (long)soffK);
        soffQ += 64; soffK += 64;
      } else {
        char* vn = smem + 32768;  // vbuf0 prefetch for PV pk0
#pragma unroll
        for (int r = 0; r < 4; ++r) {
          gld16(vn + (r * 8 + w) * 1024, Vc + (long)soffV[r]);
          soffV[r] += 64;
        }
      }
      half8 af[4], bf[2];
#pragma unroll
      for (int i = 0; i < 4; ++i) af[i] = *(const half8*)(scur + offA[i]);
#pragma unroll
      for (int j = 0; j < 2; ++j) bf[j] = *(const half8*)(scur + offB[j]);
      LGKM0();
      __builtin_amdgcn_s_setprio(1);
#pragma unroll
      for (int i = 0; i < 4; ++i)
#pragma unroll
        for (int j = 0; j < 2; ++j)
          acc_s[i][j] = __builtin_amdgcn_mfma_f32_16x16x32_f16(af[i], bf[j], acc_s[i][j], 0, 0, 0);
      __builtin_amdgcn_s_setprio(0);
      VMCNT(0);
      __builtin_amdgcn_s_barrier();
    }
    // iter boundary: Q k-reset; K next 128 rows
    soffQ -= 1024;
    soffK += 128 * NQKV * 2 - 1024;
    // ---- exp + P write + rowsum partials ----
#pragma unroll
    for (int i = 0; i < 4; ++i) {
      const int mrow = wm * 64 + i * 16 + quad * 4;
#pragma unroll
      for (int j = 0; j < 2; ++j) {
        const int n = wn * 32 + j * 16 + l16;
        const int cw = n >> 3;
        const int nlo = (n & 7) * 2;
#pragma unroll
        for (int r = 0; r < 4; ++r) {
          float v = __expf(acc_s[i][j][r]);
          rs[i][r] += v;
          const int m = mrow + r;
          *(half_t*)(smem + 98304 + m * 256 + (((cw ^ (m & 15)) << 4) | nlo)) = (half_t)v;
        }
      }
    }
    LGKM0();
    __builtin_amdgcn_s_barrier();
    // ---- PV ----
#pragma unroll
    for (int pk = 0; pk < 4; ++pk) {
      const char* vcur = smem + 32768 + (pk & 1) * 32768;
      if (pk < 3) {
        char* vn = smem + 32768 + ((pk + 1) & 1) * 32768;
#pragma unroll
        for (int r = 0; r < 4; ++r) {
          gld16(vn + (r * 8 + w) * 1024, Vc + (long)soffV[r]);
          soffV[r] += 64;
        }
      } else if (it < 7) {
        gld16(smem + w * 1024, Qc + (long)soffQ);
        gld16(smem + (8 + w) * 1024, Kc + (long)soffK);
        soffQ += 64; soffK += 64;
      }
      half8 paf[4], vb0[4];
#pragma unroll
      for (int i = 0; i < 4; ++i)
        paf[i] = *(const half8*)(smem + (offP0[i] ^ (pk << 6)));
#pragma unroll
      for (int jj = 0; jj < 4; ++jj)
        vb0[jj] = *(const half8*)(vcur + offV[jj]);
      LGKM0();
      __builtin_amdgcn_s_setprio(1);
#pragma unroll
      for (int jj = 0; jj < 4; ++jj)
#pragma unroll
        for (int i = 0; i < 4; ++i)
          acc_o[i][jj] = __builtin_amdgcn_mfma_f32_16x16x32_f16(paf[i], vb0[jj], acc_o[i][jj], 0, 0, 0);
      __builtin_amdgcn_s_setprio(0);
      half8 vb1[4];
#pragma unroll
      for (int jj = 0; jj < 4; ++jj)
        vb1[jj] = *(const half8*)(vcur + offV[4 + jj]);
      LGKM0();
      __builtin_amdgcn_s_setprio(1);
#pragma unroll
      for (int jj = 0; jj < 4; ++jj)
#pragma unroll
        for (int i = 0; i < 4; ++i)
          acc_o[i][4 + jj] = __builtin_amdgcn_mfma_f32_16x16x32_f16(paf[i], vb1[jj], acc_o[i][4 + jj], 0, 0, 0);
      __builtin_amdgcn_s_setprio(0);
      VMCNT(0);
      __builtin_amdgcn_s_barrier();
    }
  }

  // ---- rowsum atomics (once per block) ----
#pragma unroll
  for (int i = 0; i < 4; ++i)
#pragma unroll
    for (int r = 0; r < 4; ++r) {
      float v = rs[i][r];
      v += __shfl_xor(v, 1);
      v += __shfl_xor(v, 2);
      v += __shfl_xor(v, 4);
      v += __shfl_xor(v, 8);
      if (l16 == 0)
        atomicAdd(&rowsum[(long)zb * NSP + m0 + wm * 64 + i * 16 + quad * 4 + r], v);
    }

  // ---- O partial store ----
  half_t* pb = part + ((long)(zb * KSPLIT + ksp)) * NSP * CH;
#pragma unroll
  for (int i = 0; i < 4; ++i) {
    const int gm = m0 + wm * 64 + i * 16 + quad * 4;
#pragma unroll
    for (int jj = 0; jj < 8; ++jj) {
      const int gd = wd * 128 + jj * 16 + l16;
#pragma unroll
      for (int r = 0; r < 4; ++r)
        pb[(long)(gm + r) * CH + gd] = (half_t)acc_o[i][jj][r];
    }
  }
}

// ---------------- PV split-K combine: ao = (sum of slabs) / rowsum --------
__global__ __launch_bounds__(256) void pv_combine(const half_t* __restrict__ part,
                                                  const float* __restrict__ rowsum,
                                                  half_t* __restrict__ ao) {
  const long bNC = (long)NSP * CH;
  long i = ((long)blockIdx.x * 256 + threadIdx.x) * 8;
  int b = (int)(i >> 21);
  long inner = i & ((1L << 21) - 1);
  float inv = 1.f / rowsum[i >> 9];
  float s[8] = {};
#pragma unroll
  for (int ks = 0; ks < KSPLIT; ++ks) {
    half8 h = *(const half8*)(part + ((long)(b * KSPLIT + ks)) * bNC + inner);
#pragma unroll
    for (int r = 0; r < 8; ++r) s[r] += (float)h[r];
  }
  half8 o;
#pragma unroll
  for (int r = 0; r < 8; ++r) o[r] = (half_t)(s[r] * inv);
  *(half8*)(ao + i) = o;
}

extern "C" void kernel_launch(void* const* d_in, const int* in_sizes, int n_in,
                              void* d_out, int out_size, void* d_ws, size_t ws_size,
                              hipStream_t stream) {
  const float* x = (const float*)d_in[0];
  const float* gamma = (const float*)d_in[1];
  const float* beta = (const float*)d_in[2];
  const float* wq = (const float*)d_in[3];
  const float* bq = (const float*)d_in[4];
  const float* wk = (const float*)d_in[5];
  const float* bk = (const float*)d_in[6];
  const float* wv = (const float*)d_in[7];
  const float* bv = (const float*)d_in[8];
  const float* wp = (const float*)d_in[9];
  const float* bp = (const float*)d_in[10];
  float* out = (float*)d_out;
  char* ws = (char*)d_ws;

  float* st = (float*)(ws + OFF_STATS);
  float* rsum = (float*)(ws + OFF_ROWSUM);
  float* pst = (float*)(ws + OFF_PST);
  half_t* wqkvT = (half_t*)(ws + OFF_WQKV);
  half_t* wpT = (half_t*)(ws + OFF_WP);
  half_t* xn = (half_t*)(ws + OFF_XN);
  half_t* qkv = (half_t*)(ws + OFF_QKV);
  half_t* vt = (half_t*)(ws + OFF_VT);
  half_t* ao = (half_t*)(ws + OFF_AO);
  half_t* part = (half_t*)(ws + OFF_PART);

  half_t* q = qkv;            // ld NQKV
  half_t* k = qkv + CH;       // ld NQKV
  half_t* v = qkv + 2 * CH;   // ld NQKV

  const float scale = 0.044194173824159216f;  // 1/sqrt(512)

  gn_stats<<<dim3(256, BATCH), 256, 0, stream>>>(x, pst);
  gn_finalize<<<1, 256, 0, stream>>>(pst, st, rsum);
  gn_apply<<<2048, 256, 0, stream>>>(x, st, gamma, beta, xn);
  transpose_w<<<dim3(16, 16, 4), 256, 0, stream>>>(
      wq, wk, wv, wp, wqkvT, wqkvT + (size_t)CH * CH, wqkvT + 2 * (size_t)CH * CH, wpT);

  // fused qkv = xn @ [wq|wk|wv]^T + bias (q scaled)
  gemm_nt<128, 128, 64, 1, 2, 1, half_t><<<dim3(BATCH * NSP / 128, NQKV / 128, 1), 256, 0, stream>>>(
      xn, wqkvT, qkv, bq, bk, bv, nullptr, nullptr, BATCH * NSP, NQKV, CH,
      CH, CH, NQKV, 0, 0, 0, scale);
  transpose_v<<<dim3(16, 128, BATCH), 256, 0, stream>>>(v, vt);

  // fused attention: scores+exp+PV; partials + rowsum
  fattn<<<dim3(BATCH * NSP / 128, KSPLIT), 512, 0, stream>>>(q, k, vt, part, rsum);
  pv_combine<<<2048, 256, 0, stream>>>(part, rsum, ao);

  // out = ao @ wp^T + bp + x
  gemm_nt<64, 64, 128, 2, 2, 1, float><<<dim3(BATCH * NSP / 64, CH / 64, 1), 256, 0, stream>>>(
      ao, wpT, out, bp, nullptr, nullptr, x, nullptr, BATCH * NSP, CH, CH,
      CH, CH, CH, 0, 0, 0, 1.f);
}

// Round 5
// 278.842 us; speedup vs baseline: 1.1726x; 1.1726x over previous
//
#include <hip/hip_runtime.h>
#include <hip/hip_fp16.h>

typedef _Float16 half_t;
typedef _Float16 half8 __attribute__((ext_vector_type(8)));
typedef float floatx4 __attribute__((ext_vector_type(4)));

static constexpr int BATCH = 2;
static constexpr int NSP = 4096;   // H*W
static constexpr int CH = 512;
static constexpr int NQKV = 3 * CH;  // 1536
static constexpr int KSPLIT = 4;

// ---- ws layout (bytes) ----
static constexpr size_t OFF_STATS = 0;                              // 128 floats
static constexpr size_t OFF_ROWSUM = 512;                           // B*NSP floats (32 KB)
static constexpr size_t OFF_PST = 33280;                            // GN partials
static constexpr size_t OFF_WQKV = 196608;
static constexpr size_t WQKV_BYTES = (size_t)NQKV * CH * 2;         // 1.5 MB
static constexpr size_t OFF_WP = OFF_WQKV + WQKV_BYTES;
static constexpr size_t WP_BYTES = (size_t)CH * CH * 2;             // 0.5 MB
static constexpr size_t OFF_XN = OFF_WP + WP_BYTES;
static constexpr size_t XN_BYTES = (size_t)BATCH * NSP * CH * 2;    // 8 MB
static constexpr size_t OFF_QKV = OFF_XN + XN_BYTES;
static constexpr size_t QKV_BYTES = (size_t)BATCH * NSP * NQKV * 2; // 24 MB
static constexpr size_t OFF_VT = OFF_QKV + QKV_BYTES;
static constexpr size_t OFF_AO = OFF_VT + XN_BYTES;
static constexpr size_t OFF_S = OFF_AO + XN_BYTES;
static constexpr size_t S_BYTES_1 = (size_t)NSP * NSP * 2;          // 32 MB / batch
// PV split-K partials: 8 slabs x 4 MB = 32 MB, overlaying xn+qkv (dead by PV)
static constexpr size_t OFF_PART = OFF_XN;

__device__ __forceinline__ void gld16(void* lds, const void* g) {
  __builtin_amdgcn_global_load_lds(
      (__attribute__((address_space(1))) void*)(g),
      (__attribute__((address_space(3))) void*)(lds),
      16, 0, 0);
}

#define VMCNT(n) asm volatile("s_waitcnt vmcnt(" #n ")" ::: "memory")
#define LGKM0()                                         \
  do {                                                  \
    asm volatile("s_waitcnt lgkmcnt(0)" ::: "memory");  \
    __builtin_amdgcn_sched_barrier(0);                  \
  } while (0)

// ---------------- GroupNorm ----------------
__global__ __launch_bounds__(256) void gn_stats(const float* __restrict__ x,
                                                float* __restrict__ pst) {
  int b = blockIdx.y;
  int tid = (int)threadIdx.x;
  int g = ((tid * 4) & (CH - 1)) >> 4;
  const float* base = x + (long)b * NSP * CH + (long)blockIdx.x * 16 * CH + tid * 4;
  float s = 0.f, s2 = 0.f;
#pragma unroll
  for (int it = 0; it < 8; ++it) {
    floatx4 v = *(const floatx4*)(base + (long)it * 1024);
#pragma unroll
    for (int r = 0; r < 4; ++r) { s += v[r]; s2 += v[r] * v[r]; }
  }
  __shared__ float gs[32], gs2[32];
  if (tid < 32) { gs[tid] = 0.f; gs2[tid] = 0.f; }
  __syncthreads();
  atomicAdd(&gs[g], s);
  atomicAdd(&gs2[g], s2);
  __syncthreads();
  if (tid < 32) {
    long idx = ((long)(b * 256 + blockIdx.x) * 32 + tid) * 2;
    pst[idx] = gs[tid];
    pst[idx + 1] = gs2[tid];
  }
}

__global__ __launch_bounds__(256) void gn_finalize(const float* __restrict__ pst,
                                                   float* __restrict__ st,
                                                   float* __restrict__ rowsum) {
  int tid = (int)threadIdx.x;
  int bg = tid & 63;
  int p = tid >> 6;
  int b = bg >> 5, g = bg & 31;
  float s = 0.f, s2 = 0.f;
  for (int j = 0; j < 64; ++j) {
    int chunk = p * 64 + j;
    long idx = ((long)(b * 256 + chunk) * 32 + g) * 2;
    s += pst[idx];
    s2 += pst[idx + 1];
  }
  __shared__ float rs[64][4], rs2[64][4];
  rs[bg][p] = s;
  rs2[bg][p] = s2;
  __syncthreads();
  if (tid < 64) {
    float ts = rs[tid][0] + rs[tid][1] + rs[tid][2] + rs[tid][3];
    float ts2 = rs2[tid][0] + rs2[tid][1] + rs2[tid][2] + rs2[tid][3];
    const float inv = 1.f / 65536.f;
    float mean = ts * inv;
    float var = ts2 * inv - mean * mean;
    st[tid * 2] = mean;
    st[tid * 2 + 1] = rsqrtf(var + 1e-5f);
  }
  floatx4* rz = (floatx4*)rowsum;
#pragma unroll
  for (int j = 0; j < 8; ++j)
    rz[tid + j * 256] = floatx4{0.f, 0.f, 0.f, 0.f};
}

__global__ __launch_bounds__(256) void gn_apply(const float* __restrict__ x,
                                                const float* __restrict__ st,
                                                const float* __restrict__ gamma,
                                                const float* __restrict__ beta,
                                                half_t* __restrict__ xn) {
  long i = ((long)blockIdx.x * 256 + threadIdx.x) * 8;
  int c = (int)(i & (CH - 1));
  int b = (int)(i >> 21);
  int g = c >> 4;
  float mean = st[((b << 5) + g) * 2];
  float rstd = st[((b << 5) + g) * 2 + 1];
  floatx4 a = *(const floatx4*)(x + i);
  floatx4 d = *(const floatx4*)(x + i + 4);
  half8 o;
#pragma unroll
  for (int r = 0; r < 4; ++r) {
    o[r]     = (half_t)((a[r] - mean) * rstd * gamma[c + r] + beta[c + r]);
    o[r + 4] = (half_t)((d[r] - mean) * rstd * gamma[c + r + 4] + beta[c + r + 4]);
  }
  *(half8*)(xn + i) = o;
}

// ---------------- transposes ----------------
__global__ __launch_bounds__(256) void transpose_w(
    const float* __restrict__ w0, const float* __restrict__ w1,
    const float* __restrict__ w2, const float* __restrict__ w3,
    half_t* __restrict__ o0, half_t* __restrict__ o1,
    half_t* __restrict__ o2, half_t* __restrict__ o3) {
  const float* w; half_t* o;
  switch (blockIdx.z) {
    case 0: w = w0; o = o0; break;
    case 1: w = w1; o = o1; break;
    case 2: w = w2; o = o2; break;
    default: w = w3; o = o3; break;
  }
  __shared__ float t[32][33];
  int d0 = blockIdx.x * 32, c0 = blockIdx.y * 32;
  int tx = threadIdx.x & 31, ty = threadIdx.x >> 5;
#pragma unroll
  for (int i = 0; i < 4; ++i)
    t[ty + i * 8][tx] = w[(long)(c0 + ty + i * 8) * CH + d0 + tx];
  __syncthreads();
#pragma unroll
  for (int i = 0; i < 4; ++i) {
    int d = ty + i * 8;
    o[(long)(d0 + d) * CH + c0 + tx] = (half_t)t[tx][d];
  }
}

__global__ __launch_bounds__(256) void transpose_v(const half_t* __restrict__ v,
                                                   half_t* __restrict__ vt) {
  __shared__ half_t t[32][33];
  int b = blockIdx.z;
  int d0 = blockIdx.x * 32, n0 = blockIdx.y * 32;
  int tx = threadIdx.x & 31, ty = threadIdx.x >> 5;
  const half_t* vb = v + (long)b * NSP * NQKV;
  half_t* ob = vt + (long)b * NSP * CH;
#pragma unroll
  for (int i = 0; i < 4; ++i)
    t[ty + i * 8][tx] = vb[(long)(n0 + ty + i * 8) * NQKV + d0 + tx];
  __syncthreads();
#pragma unroll
  for (int i = 0; i < 4; ++i) {
    int d = ty + i * 8;
    ob[(long)(d0 + d) * NSP + n0 + tx] = t[tx][d];
  }
}

// ---------------- NT GEMM (QKV + proj) ----------------
template <int BM, int BN, int BK, int EPI, int SWZ, int KSP, typename OutT>
__global__ __launch_bounds__(256) void gemm_nt(
    const half_t* __restrict__ X, const half_t* __restrict__ Y,
    OutT* __restrict__ Co, const float* __restrict__ b0,
    const float* __restrict__ b1, const float* __restrict__ b2,
    const float* __restrict__ resid, float* __restrict__ rowsum,
    int M, int N, int K, int ldx, int ldy, int ldc,
    long xbs, long ybs, long cbs, float scale) {
  constexpr int SM = BM / 32;
  constexpr int SN = BN / 32;
  constexpr int ROWS = BM + BN;
  constexpr int CPR = BK / 8;
  constexpr int RPW = 64 / CPR;
  constexpr int ROUNDS = (ROWS * BK * 2) / 4096;
  constexpr int KSTEPS = BK / 32;
  static_assert(BM % (4 * RPW) == 0, "no As/Bs straddle within a round");
  __shared__ __align__(16) half_t Sh[ROWS * BK];

  const int zb = blockIdx.z / KSP;
  const int ks = blockIdx.z % KSP;
  int bx, by;
  if (SWZ == 1) {
    int lin = (int)(blockIdx.x + gridDim.x * blockIdx.y);
    int wmt = 256 / (int)gridDim.x;
    by = wmt * (lin >> 8) + ((lin & 255) % wmt);
    bx = (lin & 255) / wmt;
  } else if (SWZ == 2) {
    by = blockIdx.x;
    bx = blockIdx.y;
  } else {
    bx = blockIdx.x;
    by = blockIdx.y;
  }

  const half_t* Xb = X + (long)zb * xbs + (long)ks * K;
  const half_t* Yb = Y + (long)zb * ybs + (long)ks * K;
  OutT* Cb = Co + (long)blockIdx.z * cbs;

  const int m0 = by * BM;
  const int n0 = bx * BN;
  const int tid = (int)threadIdx.x;
  const int wave = tid >> 6;
  const int lane = tid & 63;
  const int quad = lane >> 4;
  const int l16 = lane & 15;
  const int wm = wave >> 1;
  const int wn = wave & 1;

  floatx4 acc[SM][SN] = {};

  const int srow = lane / CPR;
  const int schunk = lane % CPR;
  const char* Xc = (const char*)Xb;

  int soff[ROUNDS];
#pragma unroll
  for (int r = 0; r < ROUNDS; ++r) {
    int row = r * (4 * RPW) + wave * RPW + srow;
    int gchunk = schunk ^ (row & (CPR - 1));
    const char* p = (row < BM)
        ? (const char*)(Xb + (long)(m0 + row) * ldx)
        : (const char*)(Yb + (long)(n0 + row - BM) * ldy);
    soff[r] = (int)(p + gchunk * 16 - Xc);
  }

  int offA[SM], offB[SN];
#pragma unroll
  for (int i = 0; i < SM; ++i) {
    int m = wm * (BM / 2) + i * 16 + l16;
    int cc = quad ^ (m & (CPR - 1));
    offA[i] = (m * BK + cc * 8) * 2;
  }
#pragma unroll
  for (int j = 0; j < SN; ++j) {
    int n = wn * (BN / 2) + j * 16 + l16;
    int cc = quad ^ (n & (CPR - 1));
    offB[j] = (BM * BK + n * BK + cc * 8) * 2;
  }

  for (int k0 = 0; k0 < K; k0 += BK) {
#pragma unroll
    for (int r = 0; r < ROUNDS; ++r) {
      gld16((char*)Sh + (r * 4 + wave) * 1024, Xc + (long)soff[r]);
      soff[r] += BK * 2;
    }
    __syncthreads();

#pragma unroll
    for (int kk = 0; kk < KSTEPS; ++kk) {
      const int kx = kk << 6;
      half8 af[SM], bf[SN];
#pragma unroll
      for (int i = 0; i < SM; ++i)
        af[i] = *(const half8*)((const char*)Sh + (offA[i] ^ kx));
#pragma unroll
      for (int j = 0; j < SN; ++j)
        bf[j] = *(const half8*)((const char*)Sh + (offB[j] ^ kx));
#pragma unroll
      for (int i = 0; i < SM; ++i)
#pragma unroll
        for (int j = 0; j < SN; ++j)
          acc[i][j] = __builtin_amdgcn_mfma_f32_16x16x32_f16(af[i], bf[j], acc[i][j], 0, 0, 0);
    }
    __syncthreads();
  }

#pragma unroll
  for (int i = 0; i < SM; ++i) {
    int gmb = m0 + wm * (BM / 2) + i * 16 + quad * 4;
#pragma unroll
    for (int j = 0; j < SN; ++j) {
      int gn = n0 + wn * (BN / 2) + j * 16 + l16;
      float bias = 0.f, sc = 1.f;
      if (EPI == 1) {
        if (gn < CH) { bias = b0[gn]; sc = scale; }
        else if (gn < 2 * CH) { bias = b1[gn - CH]; }
        else { bias = b2[gn - 2 * CH]; }
      } else if (EPI == 2) {
        bias = b0[gn];
      }
#pragma unroll
      for (int r = 0; r < 4; ++r) {
        long idx = (long)(gmb + r) * ldc + gn;
        float v = acc[i][j][r];
        if (EPI == 1) v = (v + bias) * sc;
        if (EPI == 2) v = v + bias + resid[idx];
        Cb[idx] = (OutT)v;
      }
    }
  }
}

// ---------------- 8-phase 256x256 NT GEMM, schedule A/B probe ----------
// SCHED 0: r2 schedule (1 barrier/phase, hoisted A-reads, kk-inner MFMA).
// SCHED 1: m201-faithful: this-phase reads issued PRE-barrier (latency
//          overlaps barrier convergence), 2 barriers/phase, kk-OUTER MFMA
//          (8 independent MFMAs between dependent same-acc pairs).
//          Hazards re-verified: every pre-barrier read targets rounds
//          disjoint from this phase's staging; overwritten rounds' last
//          reader certified >=1 barrier earlier; vmcnt counts unchanged
//          (staging stays in the same inter-barrier window as r1/r2).
// SCHED 2: r2 schedule but kk-OUTER MFMA (isolates MFMA-order factor).
template <int EPI, int KSP, int SCHED, typename OutT>
__global__ __launch_bounds__(512, 2) void gemm8p(
    const half_t* __restrict__ X, const half_t* __restrict__ Y,
    OutT* __restrict__ Co, float* __restrict__ rowsum,
    int K, int ldx, int ldy, int ldc, long xbs, long ybs, long cbs) {
  __shared__ __align__(16) char smem[131072];
  const int zb = (int)blockIdx.z / KSP;
  const int ks = (int)blockIdx.z % KSP;
  const int m0 = (int)blockIdx.x * 256;  // m-major grid
  const int n0 = (int)blockIdx.y * 256;
  const int tid = (int)threadIdx.x;
  const int w = tid >> 6;
  const int l = tid & 63;
  const int quad = l >> 4;
  const int l16 = l & 15;
  const int wm = w >> 2;
  const int wn = w & 3;

  const half_t* Xb = X + (long)zb * xbs + (long)ks * K;
  const half_t* Yb = Y + (long)zb * ybs + (long)ks * K;
  OutT* Cb = Co + (long)blockIdx.z * cbs;
  const char* Xc = (const char*)Xb;

  int soff[8];
  {
    const int lr = l >> 3;
    const int g = (l & 7) ^ (lr & 7);
#pragma unroll
    for (int r = 0; r < 8; ++r) {
      const int R = (r * 8 + w) * 8 + lr;
      const char* p = (R < 256)
          ? (const char*)(Xb + (long)(m0 + R) * ldx)
          : (const char*)(Yb + (long)(n0 + R - 256) * ldy);
      soff[r] = (int)(p + g * 16 - Xc);
    }
  }

  int offA[8], offB[4];
#pragma unroll
  for (int i = 0; i < 8; ++i) {
    const int m = wm * 128 + i * 16 + l16;
    offA[i] = m * 128 + ((quad ^ (m & 7)) << 4);
  }
#pragma unroll
  for (int j = 0; j < 4; ++j) {
    const int n = wn * 64 + j * 16 + l16;
    offB[j] = 32768 + n * 128 + ((quad ^ (n & 7)) << 4);
  }

  floatx4 acc[8][4] = {};

  // prologue: tile0 full -> buf0; tile1 {4,5,6,7,0,2} -> buf1
#pragma unroll
  for (int r = 0; r < 8; ++r) {
    gld16(smem + (r * 8 + w) * 1024, Xc + (long)soff[r]);
    soff[r] += 128;
  }
  {
    constexpr int pr[6] = {4, 5, 6, 7, 0, 2};
#pragma unroll
    for (int t = 0; t < 6; ++t) {
      gld16(smem + 65536 + (pr[t] * 8 + w) * 1024, Xc + (long)soff[pr[t]]);
      soff[pr[t]] += 128;
    }
  }
  VMCNT(6);
  __builtin_amdgcn_s_barrier();

  const int NI = K >> 7;  // 2 K-tiles per iteration
  half8 bf[4][2];
  for (int it = 0; it < NI; ++it) {
    const bool last = (it == NI - 1);
    constexpr int sr0[8] = {1, 4, 6, 0, 1, 4, 6, 0};
    constexpr int sr1[8] = {3, 5, 7, 2, 3, 5, 7, 2};
    constexpr int spar[8] = {1, 0, 0, 0, 0, 1, 1, 1};
    constexpr int hoist[8] = {1, 1, 1, 0, 1, 0, 1, 0};
    half8 af[2][2];
#pragma unroll
    for (int ph = 0; ph < 8; ++ph) {
      const int q = ph & 3;
      const char* bb = smem + (ph >> 2) * 65536;
      if (SCHED == 1) {
        // -------- m201-faithful phase --------
        if (q == 0) {
#pragma unroll
          for (int j = 0; j < 4; ++j)
#pragma unroll
            for (int kk = 0; kk < 2; ++kk)
              bf[j][kk] = *(const half8*)(bb + (offB[j] ^ (kk << 6)));
        }
#pragma unroll
        for (int i2 = 0; i2 < 2; ++i2)
#pragma unroll
          for (int kk = 0; kk < 2; ++kk)
            af[i2][kk] = *(const half8*)(bb + (offA[q * 2 + i2] ^ (kk << 6)));
        if (ph == 0 || !last) {
          const int r0 = sr0[ph], r1 = sr1[ph];
          char* db = smem + spar[ph] * 65536;
          gld16(db + (r0 * 8 + w) * 1024, Xc + (long)soff[r0]);
          soff[r0] += 128;
          gld16(db + (r1 * 8 + w) * 1024, Xc + (long)soff[r1]);
          soff[r1] += 128;
        }
        __builtin_amdgcn_s_barrier();
        LGKM0();
        __builtin_amdgcn_s_setprio(1);
#pragma unroll
        for (int kk = 0; kk < 2; ++kk)
#pragma unroll
          for (int i2 = 0; i2 < 2; ++i2)
#pragma unroll
            for (int j = 0; j < 4; ++j)
              acc[q * 2 + i2][j] = __builtin_amdgcn_mfma_f32_16x16x32_f16(
                  af[i2][kk], bf[j][kk], acc[q * 2 + i2][j], 0, 0, 0);
        __builtin_amdgcn_s_setprio(0);
        if (ph == 3) {
          if (last) { VMCNT(2); } else { VMCNT(8); }
        } else if (ph == 5) {
          if (last) { VMCNT(0); } else { VMCNT(10); }
        } else if (ph == 7) {
          if (!last) { VMCNT(6); }
        }
        __builtin_amdgcn_s_barrier();
      } else {
        // -------- r2 schedule (hoisted, 1 barrier) --------
        if (q == 0) {
#pragma unroll
          for (int j = 0; j < 4; ++j)
#pragma unroll
            for (int kk = 0; kk < 2; ++kk)
              bf[j][kk] = *(const half8*)(bb + (offB[j] ^ (kk << 6)));
#pragma unroll
          for (int i2 = 0; i2 < 2; ++i2)
#pragma unroll
            for (int kk = 0; kk < 2; ++kk)
              af[i2][kk] = *(const half8*)(bb + (offA[i2] ^ (kk << 6)));
        } else if (ph == 6) {
#pragma unroll
          for (int i2 = 0; i2 < 2; ++i2)
#pragma unroll
            for (int kk = 0; kk < 2; ++kk)
              af[i2][kk] = *(const half8*)(bb + (offA[q * 2 + i2] ^ (kk << 6)));
        }
        if (ph == 0 || !last) {
          const int r0 = sr0[ph], r1 = sr1[ph];
          char* db = smem + spar[ph] * 65536;
          gld16(db + (r0 * 8 + w) * 1024, Xc + (long)soff[r0]);
          soff[r0] += 128;
          gld16(db + (r1 * 8 + w) * 1024, Xc + (long)soff[r1]);
          soff[r1] += 128;
        }
        LGKM0();
        __builtin_amdgcn_s_setprio(1);
        if (SCHED == 2) {
#pragma unroll
          for (int kk = 0; kk < 2; ++kk)
#pragma unroll
            for (int i2 = 0; i2 < 2; ++i2)
#pragma unroll
              for (int j = 0; j < 4; ++j)
                acc[q * 2 + i2][j] = __builtin_amdgcn_mfma_f32_16x16x32_f16(
                    af[i2][kk], bf[j][kk], acc[q * 2 + i2][j], 0, 0, 0);
        } else {
#pragma unroll
          for (int i2 = 0; i2 < 2; ++i2)
#pragma unroll
            for (int j = 0; j < 4; ++j)
#pragma unroll
              for (int kk = 0; kk < 2; ++kk)
                acc[q * 2 + i2][j] = __builtin_amdgcn_mfma_f32_16x16x32_f16(
                    af[i2][kk], bf[j][kk], acc[q * 2 + i2][j], 0, 0, 0);
        }
        __builtin_amdgcn_s_setprio(0);
        if (ph == 3) {
          if (last) { VMCNT(2); } else { VMCNT(8); }
        } else if (ph == 5) {
          if (last) { VMCNT(0); } else { VMCNT(10); }
        }
        if (hoist[ph]) {
          const int np = ph + 1;
          const int nq = np & 3;
          const char* nb = smem + ((np >> 2) & 1) * 65536;
#pragma unroll
          for (int i2 = 0; i2 < 2; ++i2)
#pragma unroll
            for (int kk = 0; kk < 2; ++kk)
              af[i2][kk] = *(const half8*)(nb + (offA[nq * 2 + i2] ^ (kk << 6)));
          __builtin_amdgcn_sched_barrier(0);
        }
        if (ph == 7) {
          if (!last) { VMCNT(6); }
        }
        __builtin_amdgcn_s_barrier();
      }
    }
  }

  // epilogue
#pragma unroll
  for (int i = 0; i < 8; ++i) {
    const int gmb = m0 + wm * 128 + i * 16 + quad * 4;
    float rs[4] = {0.f, 0.f, 0.f, 0.f};
#pragma unroll
    for (int j = 0; j < 4; ++j) {
      const int gn = n0 + wn * 64 + j * 16 + l16;
#pragma unroll
      for (int r = 0; r < 4; ++r) {
        long idx = (long)(gmb + r) * ldc + gn;
        float v = acc[i][j][r];
        if (EPI == 3) { v = __expf(v); rs[r] += v; }
        Cb[idx] = (OutT)v;
      }
    }
    if (EPI == 3) {
#pragma unroll
      for (int r = 0; r < 4; ++r) {
        float v = rs[r];
        v += __shfl_xor(v, 1);
        v += __shfl_xor(v, 2);
        v += __shfl_xor(v, 4);
        v += __shfl_xor(v, 8);
        if (l16 == 0) atomicAdd(&rowsum[(long)zb * NSP + gmb + r], v);
      }
    }
  }
}

// ---------------- PV split-K combine: ao = (sum of slabs) / rowsum --------
__global__ __launch_bounds__(256) void pv_combine(const half_t* __restrict__ part,
                                                  const float* __restrict__ rowsum,
                                                  half_t* __restrict__ ao) {
  const long bNC = (long)NSP * CH;
  long i = ((long)blockIdx.x * 256 + threadIdx.x) * 8;
  int b = (int)(i >> 21);
  long inner = i & ((1L << 21) - 1);
  float inv = 1.f / rowsum[i >> 9];
  float s[8] = {};
#pragma unroll
  for (int ks = 0; ks < KSPLIT; ++ks) {
    half8 h = *(const half8*)(part + ((long)(b * KSPLIT + ks)) * bNC + inner);
#pragma unroll
    for (int r = 0; r < 8; ++r) s[r] += (float)h[r];
  }
  half8 o;
#pragma unroll
  for (int r = 0; r < 8; ++r) o[r] = (half_t)(s[r] * inv);
  *(half8*)(ao + i) = o;
}

extern "C" void kernel_launch(void* const* d_in, const int* in_sizes, int n_in,
                              void* d_out, int out_size, void* d_ws, size_t ws_size,
                              hipStream_t stream) {
  const float* x = (const float*)d_in[0];
  const float* gamma = (const float*)d_in[1];
  const float* beta = (const float*)d_in[2];
  const float* wq = (const float*)d_in[3];
  const float* bq = (const float*)d_in[4];
  const float* wk = (const float*)d_in[5];
  const float* bk = (const float*)d_in[6];
  const float* wv = (const float*)d_in[7];
  const float* bv = (const float*)d_in[8];
  const float* wp = (const float*)d_in[9];
  const float* bp = (const float*)d_in[10];
  float* out = (float*)d_out;
  char* ws = (char*)d_ws;

  float* st = (float*)(ws + OFF_STATS);
  float* rsum = (float*)(ws + OFF_ROWSUM);
  float* pst = (float*)(ws + OFF_PST);
  half_t* wqkvT = (half_t*)(ws + OFF_WQKV);
  half_t* wpT = (half_t*)(ws + OFF_WP);
  half_t* xn = (half_t*)(ws + OFF_XN);
  half_t* qkv = (half_t*)(ws + OFF_QKV);
  half_t* vt = (half_t*)(ws + OFF_VT);
  half_t* ao = (half_t*)(ws + OFF_AO);
  half_t* S = (half_t*)(ws + OFF_S);
  half_t* part = (half_t*)(ws + OFF_PART);

  half_t* q = qkv;            // ld NQKV
  half_t* k = qkv + CH;       // ld NQKV
  half_t* v = qkv + 2 * CH;   // ld NQKV

  const float scale = 0.044194173824159216f;  // 1/sqrt(512)
  const long bQKV = (long)NSP * NQKV;
  const long bNC = (long)NSP * CH;
  const long bNN = (long)NSP * NSP;

  gn_stats<<<dim3(256, BATCH), 256, 0, stream>>>(x, pst);
  gn_finalize<<<1, 256, 0, stream>>>(pst, st, rsum);
  gn_apply<<<2048, 256, 0, stream>>>(x, st, gamma, beta, xn);
  transpose_w<<<dim3(16, 16, 4), 256, 0, stream>>>(
      wq, wk, wv, wp, wqkvT, wqkvT + (size_t)CH * CH, wqkvT + 2 * (size_t)CH * CH, wpT);

  // fused qkv = xn @ [wq|wk|wv]^T + bias (q scaled)
  gemm_nt<128, 128, 64, 1, 2, 1, half_t><<<dim3(BATCH * NSP / 128, NQKV / 128, 1), 256, 0, stream>>>(
      xn, wqkvT, qkv, bq, bk, bv, nullptr, nullptr, BATCH * NSP, NQKV, CH,
      CH, CH, NQKV, 0, 0, 0, scale);
  transpose_v<<<dim3(16, 128, BATCH), 256, 0, stream>>>(v, vt);

  bool full = ws_size >= OFF_S + 2 * S_BYTES_1;
  if (full) {
    // A/B probe: scores batch0 = SCHED0 (r2), batch1 = SCHED1 (m201-style).
    gemm8p<3, 1, 0, half_t><<<dim3(16, 16, 1), 512, 0, stream>>>(
        q, k, S, rsum, CH, NQKV, NQKV, NSP, 0, 0, 0);
    gemm8p<3, 1, 1, half_t><<<dim3(16, 16, 1), 512, 0, stream>>>(
        q + bQKV, k + bQKV, S + bNN, rsum + NSP, CH, NQKV, NQKV, NSP, 0, 0, 0);
    // PV: batch0 = SCHED0, batch1 = SCHED2 (kk-outer only).
    gemm8p<0, KSPLIT, 0, half_t><<<dim3(16, 2, KSPLIT), 512, 0, stream>>>(
        S, vt, part, nullptr, NSP / KSPLIT, NSP, NSP, CH, 0, 0, bNC);
    gemm8p<0, KSPLIT, 2, half_t><<<dim3(16, 2, KSPLIT), 512, 0, stream>>>(
        S + bNN, vt + bNC, part + (long)KSPLIT * bNC, nullptr,
        NSP / KSPLIT, NSP, NSP, CH, 0, 0, bNC);
    pv_combine<<<2048, 256, 0, stream>>>(part, rsum, ao);
  } else {
    for (int bb = 0; bb < BATCH; ++bb) {
      if (bb == 0) {
        gemm8p<3, 1, 0, half_t><<<dim3(16, 16, 1), 512, 0, stream>>>(
            q, k, S, rsum, CH, NQKV, NQKV, NSP, 0, 0, 0);
        gemm8p<0, KSPLIT, 0, half_t><<<dim3(16, 2, KSPLIT), 512, 0, stream>>>(
            S, vt, part, nullptr, NSP / KSPLIT, NSP, NSP, CH, 0, 0, bNC);
      } else {
        gemm8p<3, 1, 1, half_t><<<dim3(16, 16, 1), 512, 0, stream>>>(
            q + bQKV, k + bQKV, S, rsum + NSP, CH, NQKV, NQKV, NSP, 0, 0, 0);
        gemm8p<0, KSPLIT, 2, half_t><<<dim3(16, 2, KSPLIT), 512, 0, stream>>>(
            S, vt + bNC, part + (long)KSPLIT * bNC, nullptr,
            NSP / KSPLIT, NSP, NSP, CH, 0, 0, bNC);
      }
    }
    pv_combine<<<2048, 256, 0, stream>>>(part, rsum, ao);
  }
  // out = ao @ wp^T + bp + x
  gemm_nt<64, 64, 128, 2, 2, 1, float><<<dim3(BATCH * NSP / 64, CH / 64, 1), 256, 0, stream>>>(
      ao, wpT, out, bp, nullptr, nullptr, x, nullptr, BATCH * NSP, CH, CH,
      CH, CH, CH, 0, 0, 0, 1.f);
}

// Round 6
// 236.287 us; speedup vs baseline: 1.3838x; 1.1801x over previous
//
#include <hip/hip_runtime.h>
#include <hip/hip_fp16.h>

typedef _Float16 half_t;
typedef _Float16 half8 __attribute__((ext_vector_type(8)));
typedef float floatx4 __attribute__((ext_vector_type(4)));

static constexpr int BATCH = 2;
static constexpr int NSP = 4096;   // H*W
static constexpr int CH = 512;
static constexpr int NQKV = 3 * CH;  // 1536
static constexpr int KSPLIT = 4;

// ---- ws layout (bytes) ----
static constexpr size_t OFF_STATS = 0;                              // 128 floats
static constexpr size_t OFF_ROWSUM = 512;                           // B*NSP floats (32 KB)
static constexpr size_t OFF_PST = 33280;                            // GN partials
static constexpr size_t OFF_WQKV = 196608;
static constexpr size_t WQKV_BYTES = (size_t)NQKV * CH * 2;         // 1.5 MB
static constexpr size_t OFF_WP = OFF_WQKV + WQKV_BYTES;
static constexpr size_t WP_BYTES = (size_t)CH * CH * 2;             // 0.5 MB
static constexpr size_t OFF_XN = OFF_WP + WP_BYTES;
static constexpr size_t XN_BYTES = (size_t)BATCH * NSP * CH * 2;    // 8 MB
static constexpr size_t OFF_QKV = OFF_XN + XN_BYTES;
static constexpr size_t QKV_BYTES = (size_t)BATCH * NSP * NQKV * 2; // 24 MB
static constexpr size_t OFF_VT = OFF_QKV + QKV_BYTES;
static constexpr size_t OFF_AO = OFF_VT + XN_BYTES;
static constexpr size_t OFF_S = OFF_AO + XN_BYTES;
static constexpr size_t S_BYTES_1 = (size_t)NSP * NSP * 2;          // 32 MB / batch
// PV split-K partials: 8 slabs x 4 MB = 32 MB, overlaying xn+qkv (dead by PV)
static constexpr size_t OFF_PART = OFF_XN;

__device__ __forceinline__ void gld16(void* lds, const void* g) {
  __builtin_amdgcn_global_load_lds(
      (__attribute__((address_space(1))) void*)(g),
      (__attribute__((address_space(3))) void*)(lds),
      16, 0, 0);
}

#define VMCNT(n) asm volatile("s_waitcnt vmcnt(" #n ")" ::: "memory")
#define LGKM0()                                         \
  do {                                                  \
    asm volatile("s_waitcnt lgkmcnt(0)" ::: "memory");  \
    __builtin_amdgcn_sched_barrier(0);                  \
  } while (0)

// ---------------- GroupNorm ----------------
__global__ __launch_bounds__(256) void gn_stats(const float* __restrict__ x,
                                                float* __restrict__ pst) {
  int b = blockIdx.y;
  int tid = (int)threadIdx.x;
  int g = ((tid * 4) & (CH - 1)) >> 4;
  const float* base = x + (long)b * NSP * CH + (long)blockIdx.x * 16 * CH + tid * 4;
  float s = 0.f, s2 = 0.f;
#pragma unroll
  for (int it = 0; it < 8; ++it) {
    floatx4 v = *(const floatx4*)(base + (long)it * 1024);
#pragma unroll
    for (int r = 0; r < 4; ++r) { s += v[r]; s2 += v[r] * v[r]; }
  }
  __shared__ float gs[32], gs2[32];
  if (tid < 32) { gs[tid] = 0.f; gs2[tid] = 0.f; }
  __syncthreads();
  atomicAdd(&gs[g], s);
  atomicAdd(&gs2[g], s2);
  __syncthreads();
  if (tid < 32) {
    long idx = ((long)(b * 256 + blockIdx.x) * 32 + tid) * 2;
    pst[idx] = gs[tid];
    pst[idx + 1] = gs2[tid];
  }
}

__global__ __launch_bounds__(256) void gn_finalize(const float* __restrict__ pst,
                                                   float* __restrict__ st,
                                                   float* __restrict__ rowsum) {
  int tid = (int)threadIdx.x;
  int bg = tid & 63;
  int p = tid >> 6;
  int b = bg >> 5, g = bg & 31;
  float s = 0.f, s2 = 0.f;
  for (int j = 0; j < 64; ++j) {
    int chunk = p * 64 + j;
    long idx = ((long)(b * 256 + chunk) * 32 + g) * 2;
    s += pst[idx];
    s2 += pst[idx + 1];
  }
  __shared__ float rs[64][4], rs2[64][4];
  rs[bg][p] = s;
  rs2[bg][p] = s2;
  __syncthreads();
  if (tid < 64) {
    float ts = rs[tid][0] + rs[tid][1] + rs[tid][2] + rs[tid][3];
    float ts2 = rs2[tid][0] + rs2[tid][1] + rs2[tid][2] + rs2[tid][3];
    const float inv = 1.f / 65536.f;
    float mean = ts * inv;
    float var = ts2 * inv - mean * mean;
    st[tid * 2] = mean;
    st[tid * 2 + 1] = rsqrtf(var + 1e-5f);
  }
  floatx4* rz = (floatx4*)rowsum;
#pragma unroll
  for (int j = 0; j < 8; ++j)
    rz[tid + j * 256] = floatx4{0.f, 0.f, 0.f, 0.f};
}

__global__ __launch_bounds__(256) void gn_apply(const float* __restrict__ x,
                                                const float* __restrict__ st,
                                                const float* __restrict__ gamma,
                                                const float* __restrict__ beta,
                                                half_t* __restrict__ xn) {
  long i = ((long)blockIdx.x * 256 + threadIdx.x) * 8;
  int c = (int)(i & (CH - 1));
  int b = (int)(i >> 21);
  int g = c >> 4;
  float mean = st[((b << 5) + g) * 2];
  float rstd = st[((b << 5) + g) * 2 + 1];
  floatx4 a = *(const floatx4*)(x + i);
  floatx4 d = *(const floatx4*)(x + i + 4);
  half8 o;
#pragma unroll
  for (int r = 0; r < 4; ++r) {
    o[r]     = (half_t)((a[r] - mean) * rstd * gamma[c + r] + beta[c + r]);
    o[r + 4] = (half_t)((d[r] - mean) * rstd * gamma[c + r + 4] + beta[c + r + 4]);
  }
  *(half8*)(xn + i) = o;
}

// ---------------- transposes ----------------
__global__ __launch_bounds__(256) void transpose_w(
    const float* __restrict__ w0, const float* __restrict__ w1,
    const float* __restrict__ w2, const float* __restrict__ w3,
    half_t* __restrict__ o0, half_t* __restrict__ o1,
    half_t* __restrict__ o2, half_t* __restrict__ o3) {
  const float* w; half_t* o;
  switch (blockIdx.z) {
    case 0: w = w0; o = o0; break;
    case 1: w = w1; o = o1; break;
    case 2: w = w2; o = o2; break;
    default: w = w3; o = o3; break;
  }
  __shared__ float t[32][33];
  int d0 = blockIdx.x * 32, c0 = blockIdx.y * 32;
  int tx = threadIdx.x & 31, ty = threadIdx.x >> 5;
#pragma unroll
  for (int i = 0; i < 4; ++i)
    t[ty + i * 8][tx] = w[(long)(c0 + ty + i * 8) * CH + d0 + tx];
  __syncthreads();
#pragma unroll
  for (int i = 0; i < 4; ++i) {
    int d = ty + i * 8;
    o[(long)(d0 + d) * CH + c0 + tx] = (half_t)t[tx][d];
  }
}

__global__ __launch_bounds__(256) void transpose_v(const half_t* __restrict__ v,
                                                   half_t* __restrict__ vt) {
  __shared__ half_t t[32][33];
  int b = blockIdx.z;
  int d0 = blockIdx.x * 32, n0 = blockIdx.y * 32;
  int tx = threadIdx.x & 31, ty = threadIdx.x >> 5;
  const half_t* vb = v + (long)b * NSP * NQKV;
  half_t* ob = vt + (long)b * NSP * CH;
#pragma unroll
  for (int i = 0; i < 4; ++i)
    t[ty + i * 8][tx] = vb[(long)(n0 + ty + i * 8) * NQKV + d0 + tx];
  __syncthreads();
#pragma unroll
  for (int i = 0; i < 4; ++i) {
    int d = ty + i * 8;
    ob[(long)(d0 + d) * NSP + n0 + tx] = t[tx][d];
  }
}

// ---------------- NT GEMM (QKV + proj) ----------------
template <int BM, int BN, int BK, int EPI, int SWZ, int KSP, typename OutT>
__global__ __launch_bounds__(256) void gemm_nt(
    const half_t* __restrict__ X, const half_t* __restrict__ Y,
    OutT* __restrict__ Co, const float* __restrict__ b0,
    const float* __restrict__ b1, const float* __restrict__ b2,
    const float* __restrict__ resid, float* __restrict__ rowsum,
    int M, int N, int K, int ldx, int ldy, int ldc,
    long xbs, long ybs, long cbs, float scale) {
  constexpr int SM = BM / 32;
  constexpr int SN = BN / 32;
  constexpr int ROWS = BM + BN;
  constexpr int CPR = BK / 8;
  constexpr int RPW = 64 / CPR;
  constexpr int ROUNDS = (ROWS * BK * 2) / 4096;
  constexpr int KSTEPS = BK / 32;
  static_assert(BM % (4 * RPW) == 0, "no As/Bs straddle within a round");
  __shared__ __align__(16) half_t Sh[ROWS * BK];

  const int zb = blockIdx.z / KSP;
  const int ks = blockIdx.z % KSP;
  int bx, by;
  if (SWZ == 1) {
    int lin = (int)(blockIdx.x + gridDim.x * blockIdx.y);
    int wmt = 256 / (int)gridDim.x;
    by = wmt * (lin >> 8) + ((lin & 255) % wmt);
    bx = (lin & 255) / wmt;
  } else if (SWZ == 2) {
    by = blockIdx.x;
    bx = blockIdx.y;
  } else {
    bx = blockIdx.x;
    by = blockIdx.y;
  }

  const half_t* Xb = X + (long)zb * xbs + (long)ks * K;
  const half_t* Yb = Y + (long)zb * ybs + (long)ks * K;
  OutT* Cb = Co + (long)blockIdx.z * cbs;

  const int m0 = by * BM;
  const int n0 = bx * BN;
  const int tid = (int)threadIdx.x;
  const int wave = tid >> 6;
  const int lane = tid & 63;
  const int quad = lane >> 4;
  const int l16 = lane & 15;
  const int wm = wave >> 1;
  const int wn = wave & 1;

  floatx4 acc[SM][SN] = {};

  const int srow = lane / CPR;
  const int schunk = lane % CPR;
  const char* Xc = (const char*)Xb;

  int soff[ROUNDS];
#pragma unroll
  for (int r = 0; r < ROUNDS; ++r) {
    int row = r * (4 * RPW) + wave * RPW + srow;
    int gchunk = schunk ^ (row & (CPR - 1));
    const char* p = (row < BM)
        ? (const char*)(Xb + (long)(m0 + row) * ldx)
        : (const char*)(Yb + (long)(n0 + row - BM) * ldy);
    soff[r] = (int)(p + gchunk * 16 - Xc);
  }

  int offA[SM], offB[SN];
#pragma unroll
  for (int i = 0; i < SM; ++i) {
    int m = wm * (BM / 2) + i * 16 + l16;
    int cc = quad ^ (m & (CPR - 1));
    offA[i] = (m * BK + cc * 8) * 2;
  }
#pragma unroll
  for (int j = 0; j < SN; ++j) {
    int n = wn * (BN / 2) + j * 16 + l16;
    int cc = quad ^ (n & (CPR - 1));
    offB[j] = (BM * BK + n * BK + cc * 8) * 2;
  }

  for (int k0 = 0; k0 < K; k0 += BK) {
#pragma unroll
    for (int r = 0; r < ROUNDS; ++r) {
      gld16((char*)Sh + (r * 4 + wave) * 1024, Xc + (long)soff[r]);
      soff[r] += BK * 2;
    }
    __syncthreads();

#pragma unroll
    for (int kk = 0; kk < KSTEPS; ++kk) {
      const int kx = kk << 6;
      half8 af[SM], bf[SN];
#pragma unroll
      for (int i = 0; i < SM; ++i)
        af[i] = *(const half8*)((const char*)Sh + (offA[i] ^ kx));
#pragma unroll
      for (int j = 0; j < SN; ++j)
        bf[j] = *(const half8*)((const char*)Sh + (offB[j] ^ kx));
#pragma unroll
      for (int i = 0; i < SM; ++i)
#pragma unroll
        for (int j = 0; j < SN; ++j)
          acc[i][j] = __builtin_amdgcn_mfma_f32_16x16x32_f16(af[i], bf[j], acc[i][j], 0, 0, 0);
    }
    __syncthreads();
  }

#pragma unroll
  for (int i = 0; i < SM; ++i) {
    int gmb = m0 + wm * (BM / 2) + i * 16 + quad * 4;
#pragma unroll
    for (int j = 0; j < SN; ++j) {
      int gn = n0 + wn * (BN / 2) + j * 16 + l16;
      float bias = 0.f, sc = 1.f;
      if (EPI == 1) {
        if (gn < CH) { bias = b0[gn]; sc = scale; }
        else if (gn < 2 * CH) { bias = b1[gn - CH]; }
        else { bias = b2[gn - 2 * CH]; }
      } else if (EPI == 2) {
        bias = b0[gn];
      }
#pragma unroll
      for (int r = 0; r < 4; ++r) {
        long idx = (long)(gmb + r) * ldc + gn;
        float v = acc[i][j][r];
        if (EPI == 1) v = (v + bias) * sc;
        if (EPI == 2) v = v + bias + resid[idx];
        Cb[idx] = (OutT)v;
      }
    }
  }
}

// ---------------- 8-phase 256x256 NT GEMM (r2 schedule + XCD regions) ----
// Schedule identical to r2 (1 barrier/phase, hoisted A-reads, counted
// vmcnt 8/10/6) -- r5 A/B showed schedule variants are equivalent.
// SW=1 (16x16 tile grid only): partition grid into 8 XCD regions of
// 4 m-tiles x 8 n-tiles. With lin%8 XCD round-robin, each XCD's blocks
// stay inside one region: working set 4x256KB A + 8x256KB B = 3MB <= 4MB
// L2 (plain m-major needed 4.5MB -> B-panel thrash, L3-latency staging).
// Bijective: xcd=lin&7, k=lin>>3; m=(xcd&3)*4+(k&3), n=(xcd>>2)*8+(k>>2).
template <int EPI, int KSP, int SW, typename OutT>
__global__ __launch_bounds__(512, 2) void gemm8p(
    const half_t* __restrict__ X, const half_t* __restrict__ Y,
    OutT* __restrict__ Co, float* __restrict__ rowsum,
    int K, int ldx, int ldy, int ldc, long xbs, long ybs, long cbs) {
  __shared__ __align__(16) char smem[131072];
  const int zb = (int)blockIdx.z / KSP;
  const int ks = (int)blockIdx.z % KSP;
  int by, bx;
  if (SW == 1) {
    const int lin = (int)(blockIdx.x + (blockIdx.y << 4));
    const int xcd = lin & 7;
    const int kk2 = lin >> 3;
    by = (xcd & 3) * 4 + (kk2 & 3);
    bx = (xcd >> 2) * 8 + (kk2 >> 2);
  } else {
    by = (int)blockIdx.x;
    bx = (int)blockIdx.y;
  }
  const int m0 = by * 256;
  const int n0 = bx * 256;
  const int tid = (int)threadIdx.x;
  const int w = tid >> 6;
  const int l = tid & 63;
  const int quad = l >> 4;
  const int l16 = l & 15;
  const int wm = w >> 2;
  const int wn = w & 3;

  const half_t* Xb = X + (long)zb * xbs + (long)ks * K;
  const half_t* Yb = Y + (long)zb * ybs + (long)ks * K;
  OutT* Cb = Co + (long)blockIdx.z * cbs;
  const char* Xc = (const char*)Xb;

  int soff[8];
  {
    const int lr = l >> 3;
    const int g = (l & 7) ^ (lr & 7);
#pragma unroll
    for (int r = 0; r < 8; ++r) {
      const int R = (r * 8 + w) * 8 + lr;
      const char* p = (R < 256)
          ? (const char*)(Xb + (long)(m0 + R) * ldx)
          : (const char*)(Yb + (long)(n0 + R - 256) * ldy);
      soff[r] = (int)(p + g * 16 - Xc);
    }
  }

  int offA[8], offB[4];
#pragma unroll
  for (int i = 0; i < 8; ++i) {
    const int m = wm * 128 + i * 16 + l16;
    offA[i] = m * 128 + ((quad ^ (m & 7)) << 4);
  }
#pragma unroll
  for (int j = 0; j < 4; ++j) {
    const int n = wn * 64 + j * 16 + l16;
    offB[j] = 32768 + n * 128 + ((quad ^ (n & 7)) << 4);
  }

  floatx4 acc[8][4] = {};

  // prologue: tile0 full -> buf0; tile1 {4,5,6,7,0,2} -> buf1
#pragma unroll
  for (int r = 0; r < 8; ++r) {
    gld16(smem + (r * 8 + w) * 1024, Xc + (long)soff[r]);
    soff[r] += 128;
  }
  {
    constexpr int pr[6] = {4, 5, 6, 7, 0, 2};
#pragma unroll
    for (int t = 0; t < 6; ++t) {
      gld16(smem + 65536 + (pr[t] * 8 + w) * 1024, Xc + (long)soff[pr[t]]);
      soff[pr[t]] += 128;
    }
  }
  VMCNT(6);
  __builtin_amdgcn_s_barrier();

  const int NI = K >> 7;  // 2 K-tiles per iteration
  half8 bf[4][2];
  for (int it = 0; it < NI; ++it) {
    const bool last = (it == NI - 1);
    constexpr int sr0[8] = {1, 4, 6, 0, 1, 4, 6, 0};
    constexpr int sr1[8] = {3, 5, 7, 2, 3, 5, 7, 2};
    constexpr int spar[8] = {1, 0, 0, 0, 0, 1, 1, 1};
    constexpr int hoist[8] = {1, 1, 1, 0, 1, 0, 1, 0};
    half8 af[2][2];
#pragma unroll
    for (int ph = 0; ph < 8; ++ph) {
      const int q = ph & 3;
      const char* bb = smem + (ph >> 2) * 65536;
      if (q == 0) {
#pragma unroll
        for (int j = 0; j < 4; ++j)
#pragma unroll
          for (int kk = 0; kk < 2; ++kk)
            bf[j][kk] = *(const half8*)(bb + (offB[j] ^ (kk << 6)));
#pragma unroll
        for (int i2 = 0; i2 < 2; ++i2)
#pragma unroll
          for (int kk = 0; kk < 2; ++kk)
            af[i2][kk] = *(const half8*)(bb + (offA[i2] ^ (kk << 6)));
      } else if (ph == 6) {
#pragma unroll
        for (int i2 = 0; i2 < 2; ++i2)
#pragma unroll
          for (int kk = 0; kk < 2; ++kk)
            af[i2][kk] = *(const half8*)(bb + (offA[q * 2 + i2] ^ (kk << 6)));
      }
      if (ph == 0 || !last) {
        const int r0 = sr0[ph], r1 = sr1[ph];
        char* db = smem + spar[ph] * 65536;
        gld16(db + (r0 * 8 + w) * 1024, Xc + (long)soff[r0]);
        soff[r0] += 128;
        gld16(db + (r1 * 8 + w) * 1024, Xc + (long)soff[r1]);
        soff[r1] += 128;
      }
      LGKM0();
      __builtin_amdgcn_s_setprio(1);
#pragma unroll
      for (int i2 = 0; i2 < 2; ++i2)
#pragma unroll
        for (int j = 0; j < 4; ++j)
#pragma unroll
          for (int kk = 0; kk < 2; ++kk)
            acc[q * 2 + i2][j] = __builtin_amdgcn_mfma_f32_16x16x32_f16(
                af[i2][kk], bf[j][kk], acc[q * 2 + i2][j], 0, 0, 0);
      __builtin_amdgcn_s_setprio(0);
      if (ph == 3) {
        if (last) { VMCNT(2); } else { VMCNT(8); }
      } else if (ph == 5) {
        if (last) { VMCNT(0); } else { VMCNT(10); }
      }
      if (hoist[ph]) {
        const int np = ph + 1;
        const int nq = np & 3;
        const char* nb = smem + ((np >> 2) & 1) * 65536;
#pragma unroll
        for (int i2 = 0; i2 < 2; ++i2)
#pragma unroll
          for (int kk = 0; kk < 2; ++kk)
            af[i2][kk] = *(const half8*)(nb + (offA[nq * 2 + i2] ^ (kk << 6)));
        __builtin_amdgcn_sched_barrier(0);
      }
      if (ph == 7) {
        if (!last) { VMCNT(6); }
      }
      __builtin_amdgcn_s_barrier();
    }
  }

  // epilogue
#pragma unroll
  for (int i = 0; i < 8; ++i) {
    const int gmb = m0 + wm * 128 + i * 16 + quad * 4;
    float rs[4] = {0.f, 0.f, 0.f, 0.f};
#pragma unroll
    for (int j = 0; j < 4; ++j) {
      const int gn = n0 + wn * 64 + j * 16 + l16;
#pragma unroll
      for (int r = 0; r < 4; ++r) {
        long idx = (long)(gmb + r) * ldc + gn;
        float v = acc[i][j][r];
        if (EPI == 3) { v = __expf(v); rs[r] += v; }
        Cb[idx] = (OutT)v;
      }
    }
    if (EPI == 3) {
#pragma unroll
      for (int r = 0; r < 4; ++r) {
        float v = rs[r];
        v += __shfl_xor(v, 1);
        v += __shfl_xor(v, 2);
        v += __shfl_xor(v, 4);
        v += __shfl_xor(v, 8);
        if (l16 == 0) atomicAdd(&rowsum[(long)zb * NSP + gmb + r], v);
      }
    }
  }
}

// ---------------- PV split-K combine: ao = (sum of slabs) / rowsum --------
__global__ __launch_bounds__(256) void pv_combine(const half_t* __restrict__ part,
                                                  const float* __restrict__ rowsum,
                                                  half_t* __restrict__ ao) {
  const long bNC = (long)NSP * CH;
  long i = ((long)blockIdx.x * 256 + threadIdx.x) * 8;
  int b = (int)(i >> 21);
  long inner = i & ((1L << 21) - 1);
  float inv = 1.f / rowsum[i >> 9];
  float s[8] = {};
#pragma unroll
  for (int ks = 0; ks < KSPLIT; ++ks) {
    half8 h = *(const half8*)(part + ((long)(b * KSPLIT + ks)) * bNC + inner);
#pragma unroll
    for (int r = 0; r < 8; ++r) s[r] += (float)h[r];
  }
  half8 o;
#pragma unroll
  for (int r = 0; r < 8; ++r) o[r] = (half_t)(s[r] * inv);
  *(half8*)(ao + i) = o;
}

extern "C" void kernel_launch(void* const* d_in, const int* in_sizes, int n_in,
                              void* d_out, int out_size, void* d_ws, size_t ws_size,
                              hipStream_t stream) {
  const float* x = (const float*)d_in[0];
  const float* gamma = (const float*)d_in[1];
  const float* beta = (const float*)d_in[2];
  const float* wq = (const float*)d_in[3];
  const float* bq = (const float*)d_in[4];
  const float* wk = (const float*)d_in[5];
  const float* bk = (const float*)d_in[6];
  const float* wv = (const float*)d_in[7];
  const float* bv = (const float*)d_in[8];
  const float* wp = (const float*)d_in[9];
  const float* bp = (const float*)d_in[10];
  float* out = (float*)d_out;
  char* ws = (char*)d_ws;

  float* st = (float*)(ws + OFF_STATS);
  float* rsum = (float*)(ws + OFF_ROWSUM);
  float* pst = (float*)(ws + OFF_PST);
  half_t* wqkvT = (half_t*)(ws + OFF_WQKV);
  half_t* wpT = (half_t*)(ws + OFF_WP);
  half_t* xn = (half_t*)(ws + OFF_XN);
  half_t* qkv = (half_t*)(ws + OFF_QKV);
  half_t* vt = (half_t*)(ws + OFF_VT);
  half_t* ao = (half_t*)(ws + OFF_AO);
  half_t* S = (half_t*)(ws + OFF_S);
  half_t* part = (half_t*)(ws + OFF_PART);

  half_t* q = qkv;            // ld NQKV
  half_t* k = qkv + CH;       // ld NQKV
  half_t* v = qkv + 2 * CH;   // ld NQKV

  const float scale = 0.044194173824159216f;  // 1/sqrt(512)
  const long bQKV = (long)NSP * NQKV;
  const long bNC = (long)NSP * CH;
  const long bNN = (long)NSP * NSP;

  gn_stats<<<dim3(256, BATCH), 256, 0, stream>>>(x, pst);
  gn_finalize<<<1, 256, 0, stream>>>(pst, st, rsum);
  gn_apply<<<2048, 256, 0, stream>>>(x, st, gamma, beta, xn);
  transpose_w<<<dim3(16, 16, 4), 256, 0, stream>>>(
      wq, wk, wv, wp, wqkvT, wqkvT + (size_t)CH * CH, wqkvT + 2 * (size_t)CH * CH, wpT);

  // fused qkv = xn @ [wq|wk|wv]^T + bias (q scaled)
  gemm_nt<128, 128, 64, 1, 2, 1, half_t><<<dim3(BATCH * NSP / 128, NQKV / 128, 1), 256, 0, stream>>>(
      xn, wqkvT, qkv, bq, bk, bv, nullptr, nullptr, BATCH * NSP, NQKV, CH,
      CH, CH, NQKV, 0, 0, 0, scale);
  transpose_v<<<dim3(16, 128, BATCH), 256, 0, stream>>>(v, vt);

  bool full = ws_size >= OFF_S + 2 * S_BYTES_1;
  if (full) {
    // scores -> exp(s) + row sums: 8-phase 256x256, XCD-region swizzle
    gemm8p<3, 1, 1, half_t><<<dim3(16, 16, BATCH), 512, 0, stream>>>(
        q, k, S, rsum, CH, NQKV, NQKV, NSP, bQKV, bQKV, bNN);
    // PV split-K: 8-phase 256x256, per-XCD set already L2-resident
    gemm8p<0, KSPLIT, 0, half_t><<<dim3(NSP / 256, CH / 256, BATCH * KSPLIT), 512, 0, stream>>>(
        S, vt, part, nullptr, NSP / KSPLIT, NSP, NSP, CH, bNN, bNC, bNC);
    pv_combine<<<2048, 256, 0, stream>>>(part, rsum, ao);
  } else {
    for (int bb = 0; bb < BATCH; ++bb) {
      gemm8p<3, 1, 1, half_t><<<dim3(16, 16, 1), 512, 0, stream>>>(
          q + bb * bQKV, k + bb * bQKV, S, rsum + bb * NSP, CH,
          NQKV, NQKV, NSP, 0, 0, 0);
      gemm8p<0, KSPLIT, 0, half_t><<<dim3(NSP / 256, CH / 256, KSPLIT), 512, 0, stream>>>(
          S, vt + bb * bNC, part + (long)bb * KSPLIT * bNC, nullptr,
          NSP / KSPLIT, NSP, NSP, CH, 0, 0, bNC);
    }
    pv_combine<<<2048, 256, 0, stream>>>(part, rsum, ao);
  }
  // out = ao @ wp^T + bp + x
  gemm_nt<64, 64, 128, 2, 2, 1, float><<<dim3(BATCH * NSP / 64, CH / 64, 1), 256, 0, stream>>>(
      ao, wpT, out, bp, nullptr, nullptr, x, nullptr, BATCH * NSP, CH, CH,
      CH, CH, CH, 0, 0, 0, 1.f);
}